// Round 2
// baseline (274.829 us; speedup 1.0000x reference)
//
#include <hip/hip_runtime.h>
#include <math.h>

// Problem constants (from reference setup_inputs)
constexpr int B  = 32;
constexpr int N  = 19200;
constexpr int CH = 85;   // 4 box + 1 conf + 80 cls
constexpr float EPSF = 1e-7f;

constexpr int THREADS         = 256;                 // 4 waves
constexpr int GROUPS_PER_IMG  = N * CH / 4;          // 408,000 float4-groups per image
constexpr int BLOCKS_PER_IMG  = 100;
constexpr int GROUPS_PER_BLK  = GROUPS_PER_IMG / BLOCKS_PER_IMG;  // 4080
constexpr int GRID            = B * BLOCKS_PER_IMG;  // 3200

// ws layout (doubles): [0]=sum ciou*posf, [1]=sum bce_cls*posf, [2]=sum obj,
//                      [3..34]=per-image sum posf, [35..66]=per-image sum pos_obj*posf
constexpr int WS_DOUBLES = 3 + B + B;

// BCE with logits: max(l,0) - l*t + log1p(exp(-|l|))
__device__ __forceinline__ float bce(float l, float t) {
    float sp = __logf(1.0f + __expf(-fabsf(l)));
    return fmaxf(l, 0.0f) - l * t + sp;
}

__global__ __launch_bounds__(THREADS) void loss_main(
    const float4* __restrict__ o4p, const float4* __restrict__ t4p,
    const float*  __restrict__ outp, const float*  __restrict__ tgtp,
    double* __restrict__ ws) {

    const int b      = blockIdx.x / BLOCKS_PER_IMG;           // image (uniform per block)
    const int gBegin = blockIdx.x * GROUPS_PER_BLK;
    const int gEnd   = gBegin + GROUPS_PER_BLK;

    float v0 = 0.0f, v1 = 0.0f, v2 = 0.0f, v3 = 0.0f, v4 = 0.0f;

    for (int g = gBegin + threadIdx.x; g < gEnd; g += THREADS) {
        const float4 o4 = o4p[g];
        const float4 t4 = t4p[g];
        const int e0 = g * 4;
        const int a0 = e0 / CH;            // magic-mul division
        const int r0 = e0 - a0 * CH;

        // posf for the (at most two) anchors this group touches
        float posf0 = (tgtp[(size_t)a0 * CH + 4] > 0.5f) ? 1.0f : 0.0f;
        float posf1 = 0.0f;
        if (r0 >= CH - 3) {
            posf1 = (tgtp[(size_t)(a0 + 1) * CH + 4] > 0.5f) ? 1.0f : 0.0f;
        }

        const float ov[4] = {o4.x, o4.y, o4.z, o4.w};
        const float tv[4] = {t4.x, t4.y, t4.z, t4.w};

        #pragma unroll
        for (int k = 0; k < 4; ++k) {
            int   ch   = r0 + k;
            int   a    = a0;
            float posf = posf0;
            if (ch >= CH) { ch -= CH; a = a0 + 1; posf = posf1; }
            const float o = ov[k], t = tv[k];

            if (ch >= 5) {
                // cls focal(alpha=0.5, gamma=0) summed later as 0.5/80 * Σ bce
                v1 += posf * bce(o, t);
            } else if (ch == 4) {
                // objectness: o = pconf, t = gconf; posf == (t > 0.5)
                float pos_obj = 0.75f * bce(o, 1.0f);                    // 1.5 * 0.5*ce
                float p       = 1.0f / (1.0f + __expf(-o));
                float neg_obj = 0.25f * bce(o, 0.0f) * p * sqrtf(p);     // 0.5 * 0.5*ce*p^1.5
                v2 += (posf > 0.0f) ? pos_obj : neg_obj;
                v3 += posf;
                v4 += pos_obj * posf;
            } else if (ch == 0) {
                // this lane owns anchor a's CIoU; gathers are L1/L2 hits
                const float* po = outp + (size_t)a * CH;
                const float* pt = tgtp + (size_t)a * CH;
                float pcx = po[0], pcy = po[1], pw = po[2], ph = po[3];
                float gcx = pt[0], gcy = pt[1], gw = pt[2], gh = pt[3];

                float px1 = pcx - pw * 0.5f, px2 = pcx + pw * 0.5f;
                float py1 = pcy - ph * 0.5f, py2 = pcy + ph * 0.5f;
                float gx1 = gcx - gw * 0.5f, gx2 = gcx + gw * 0.5f;
                float gy1 = gcy - gh * 0.5f, gy2 = gcy + gh * 0.5f;

                float iwd   = fmaxf(fminf(px2, gx2) - fmaxf(px1, gx1), 0.0f);
                float ihd   = fmaxf(fminf(py2, gy2) - fmaxf(py1, gy1), 0.0f);
                float inter = iwd * ihd;
                float uni   = (px2 - px1) * (py2 - py1) + (gx2 - gx1) * (gy2 - gy1) - inter;
                float iou   = inter / (uni + EPSF);

                float cw   = fmaxf(px2, gx2) - fminf(px1, gx1);
                float chh  = fmaxf(py2, gy2) - fminf(py1, gy1);
                float diag = cw * cw + chh * chh + EPSF;
                float dx   = px1 + px2 - gx1 - gx2;
                float dy   = py1 + py2 - gy1 - gy2;
                float dist = (dx * dx + dy * dy) * 0.25f;

                float w_p = px2 - px1, h_p = py2 - py1;
                float w_g = gx2 - gx1, h_g = gy2 - gy1;
                float datan = atanf(w_g / (h_g + EPSF)) - atanf(w_p / (h_p + EPSF));
                const float four_over_pi2 = 4.0f / (float)(M_PI * M_PI);
                float vv = four_over_pi2 * datan * datan;
                float aa = vv / (1.0f - iou + vv + EPSF);  // stop_gradient: fwd value unchanged
                float ciou = 1.0f - iou + dist / diag + aa * vv;

                v0 += ciou * posf;
            }
            // ch in 1..3: covered by the ch==0 lane
        }
    }

    // fold the 1/80 mean and alpha=0.5 for cls here
    v1 *= 0.5f * (1.0f / 80.0f);

    // ---- wave reduce (64 lanes) ----
    #pragma unroll
    for (int off = 32; off > 0; off >>= 1) {
        v0 += __shfl_down(v0, off);
        v1 += __shfl_down(v1, off);
        v2 += __shfl_down(v2, off);
        v3 += __shfl_down(v3, off);
        v4 += __shfl_down(v4, off);
    }

    __shared__ float red[THREADS / 64][5];
    const int wave = threadIdx.x >> 6;
    const int lane = threadIdx.x & 63;
    if (lane == 0) {
        red[wave][0] = v0; red[wave][1] = v1; red[wave][2] = v2;
        red[wave][3] = v3; red[wave][4] = v4;
    }
    __syncthreads();

    if (threadIdx.x == 0) {
        float s0 = 0, s1 = 0, s2 = 0, s3 = 0, s4 = 0;
        #pragma unroll
        for (int w = 0; w < THREADS / 64; ++w) {
            s0 += red[w][0]; s1 += red[w][1]; s2 += red[w][2];
            s3 += red[w][3]; s4 += red[w][4];
        }
        atomicAdd(&ws[0], (double)s0);
        atomicAdd(&ws[1], (double)s1);
        atomicAdd(&ws[2], (double)s2);
        atomicAdd(&ws[3 + b],     (double)s3);
        atomicAdd(&ws[3 + B + b], (double)s4);
    }
}

__global__ void loss_final(const double* __restrict__ ws, float* __restrict__ out) {
    const int lane = threadIdx.x;
    double v = 0.0;
    if (lane < B) {
        double npos = ws[3 + lane];
        if (npos < 1.0) npos = 1.0;
        v = ws[3 + B + lane] / npos;
    }
    #pragma unroll
    for (int off = 32; off > 0; off >>= 1) v += __shfl_down(v, off);

    if (lane == 0) {
        const double inv = 1.0 / ((double)N * (double)B);
        double avg_ciou   = ws[0] * inv;
        double avg_cls    = ws[1] * inv;
        double avg_obj    = ws[2] * inv;
        double avg_posobj = v / (double)B;

        double t1 = 0.5 * avg_ciou;   // BOX_W
        double t2 = 1.5 * avg_obj;    // OBJ_W
        double t3 = 1.5 * avg_cls;    // CLS_W
        out[0] = (float)(t1 + t2 + t3);
        out[1] = (float)t1;
        out[2] = (float)t2;
        out[3] = (float)t3;
        out[4] = (float)avg_posobj;
    }
}

extern "C" void kernel_launch(void* const* d_in, const int* in_sizes, int n_in,
                              void* d_out, int out_size, void* d_ws, size_t ws_size,
                              hipStream_t stream) {
    const float* outputs = (const float*)d_in[0];
    const float* targets = (const float*)d_in[1];
    double* ws = (double*)d_ws;

    hipMemsetAsync(ws, 0, WS_DOUBLES * sizeof(double), stream);
    loss_main<<<GRID, THREADS, 0, stream>>>(
        (const float4*)outputs, (const float4*)targets, outputs, targets, ws);
    loss_final<<<1, 64, 0, stream>>>(ws, (float*)d_out);
}

// Round 3
// 124.326 us; speedup vs baseline: 2.2105x; 2.2105x over previous
//
#include <hip/hip_runtime.h>
#include <math.h>

// Problem constants (from reference setup_inputs)
constexpr int B  = 32;
constexpr int N  = 19200;
constexpr int CH = 85;   // 4 box + 1 conf + 80 cls
constexpr float EPSF = 1e-7f;

constexpr int THREADS = 256;                     // 4 waves
constexpr int TILE_A  = 64;                      // anchors per tile
constexpr int TILE_F  = TILE_A * CH;             // 5440 floats per tensor
constexpr int TILE_F4 = TILE_F / 4;              // 1360 float4 (16B-aligned: 64*85*4 = 21760 % 16 == 0)
constexpr int TILES_PER_IMG   = N / TILE_A;      // 300
constexpr int BLOCKS          = 640;             // 2.5 blocks/CU avg; LDS allows 3
constexpr int BLOCKS_PER_IMG  = BLOCKS / B;      // 20
constexpr int TILES_PER_BLOCK = TILES_PER_IMG / BLOCKS_PER_IMG;  // 15

// ws layout (doubles): [0]=sum ciou*posf, [1]=sum bce_cls*posf (scaled), [2]=sum obj,
//                      [3..34]=per-image sum posf, [35..66]=per-image sum pos_obj*posf
constexpr int WS_DOUBLES = 3 + B + B;

// BCE with logits: max(l,0) - l*t + log1p(exp(-|l|))
__device__ __forceinline__ float bce(float l, float t) {
    float sp = __logf(1.0f + __expf(-fabsf(l)));
    return fmaxf(l, 0.0f) - l * t + sp;
}

__global__ __launch_bounds__(THREADS) void loss_main(
    const float* __restrict__ outp, const float* __restrict__ tgtp,
    double* __restrict__ ws) {

    __shared__ float4 lds4[2 * TILE_F4];          // 43,520 B: [0..1360)=outputs tile, [1360..2720)=targets tile
    float* ldsf = (float*)lds4;

    const int bimg = blockIdx.x / BLOCKS_PER_IMG;                 // image (uniform per block)
    const int t0   = bimg * TILES_PER_IMG
                   + (blockIdx.x % BLOCKS_PER_IMG) * TILES_PER_BLOCK;

    const int tid = threadIdx.x;
    const int a   = tid >> 2;      // anchor within tile (0..63)
    const int q   = tid & 3;       // channel-quarter (0..3)

    float v0 = 0.0f, v1 = 0.0f, v2 = 0.0f, v3 = 0.0f, v4 = 0.0f;

    for (int t = t0; t < t0 + TILES_PER_BLOCK; ++t) {
        // ---- coalesced stage: global float4 -> LDS ----
        const float4* go = (const float4*)outp + (size_t)t * TILE_F4;
        const float4* gt = (const float4*)tgtp + (size_t)t * TILE_F4;
        for (int i = tid; i < TILE_F4; i += THREADS) {
            lds4[i]           = go[i];
            lds4[TILE_F4 + i] = gt[i];
        }
        __syncthreads();

        // ---- per-anchor compute from LDS (stride 85 floats: odd -> bank-conflict-free) ----
        const float* lo = ldsf + a * CH;              // this anchor's outputs
        const float* lt = ldsf + TILE_F + a * CH;     // this anchor's targets

        const float gconf = lt[4];                    // broadcast across the 4 q-lanes
        const float posf  = (gconf > 0.5f) ? 1.0f : 0.0f;

        // 20 cls channels per lane, compile-time offsets, branch-free
        float s = 0.0f;
        const int c0 = 5 + 20 * q;
        #pragma unroll
        for (int j = 0; j < 20; ++j) {
            s += bce(lo[c0 + j], lt[c0 + j]);
        }
        v1 += posf * s;

        if (q == 0) {
            // objectness (one masked 16-lane pass per wave)
            const float o = lo[4];
            float pos_obj = 0.75f * bce(o, 1.0f);                 // 1.5 * 0.5*ce(l,1)
            float p       = 1.0f / (1.0f + __expf(-o));
            float neg_obj = 0.25f * bce(o, 0.0f) * p * sqrtf(p);  // 0.5 * 0.5*ce(l,0)*p^1.5
            v2 += (posf > 0.0f) ? pos_obj : neg_obj;
            v3 += posf;
            v4 += pos_obj * posf;
        }
        if (q == 1) {
            // CIoU (one masked 16-lane pass per wave)
            float pcx = lo[0], pcy = lo[1], pw = lo[2], ph = lo[3];
            float gcx = lt[0], gcy = lt[1], gw = lt[2], gh = lt[3];

            float px1 = pcx - pw * 0.5f, px2 = pcx + pw * 0.5f;
            float py1 = pcy - ph * 0.5f, py2 = pcy + ph * 0.5f;
            float gx1 = gcx - gw * 0.5f, gx2 = gcx + gw * 0.5f;
            float gy1 = gcy - gh * 0.5f, gy2 = gcy + gh * 0.5f;

            float iwd   = fmaxf(fminf(px2, gx2) - fmaxf(px1, gx1), 0.0f);
            float ihd   = fmaxf(fminf(py2, gy2) - fmaxf(py1, gy1), 0.0f);
            float inter = iwd * ihd;
            float uni   = (px2 - px1) * (py2 - py1) + (gx2 - gx1) * (gy2 - gy1) - inter;
            float iou   = inter / (uni + EPSF);

            float cw   = fmaxf(px2, gx2) - fminf(px1, gx1);
            float chh  = fmaxf(py2, gy2) - fminf(py1, gy1);
            float diag = cw * cw + chh * chh + EPSF;
            float dx   = px1 + px2 - gx1 - gx2;
            float dy   = py1 + py2 - gy1 - gy2;
            float dist = (dx * dx + dy * dy) * 0.25f;

            float w_p = px2 - px1, h_p = py2 - py1;
            float w_g = gx2 - gx1, h_g = gy2 - gy1;
            float datan = atanf(w_g / (h_g + EPSF)) - atanf(w_p / (h_p + EPSF));
            const float four_over_pi2 = 4.0f / (float)(M_PI * M_PI);
            float vv = four_over_pi2 * datan * datan;
            float aa = vv / (1.0f - iou + vv + EPSF);   // stop_gradient: fwd value unchanged
            float ciou = 1.0f - iou + dist / diag + aa * vv;

            v0 += ciou * posf;
        }
        __syncthreads();   // protect LDS before next tile's staging
    }

    // fold cls alpha=0.5 and 1/80 mean
    v1 *= 0.5f * (1.0f / 80.0f);

    // ---- wave reduce (64 lanes) ----
    #pragma unroll
    for (int off = 32; off > 0; off >>= 1) {
        v0 += __shfl_down(v0, off);
        v1 += __shfl_down(v1, off);
        v2 += __shfl_down(v2, off);
        v3 += __shfl_down(v3, off);
        v4 += __shfl_down(v4, off);
    }

    __shared__ float red[THREADS / 64][5];
    const int wave = tid >> 6;
    const int lane = tid & 63;
    if (lane == 0) {
        red[wave][0] = v0; red[wave][1] = v1; red[wave][2] = v2;
        red[wave][3] = v3; red[wave][4] = v4;
    }
    __syncthreads();

    if (tid == 0) {
        float s0 = 0, s1 = 0, s2 = 0, s3 = 0, s4 = 0;
        #pragma unroll
        for (int w = 0; w < THREADS / 64; ++w) {
            s0 += red[w][0]; s1 += red[w][1]; s2 += red[w][2];
            s3 += red[w][3]; s4 += red[w][4];
        }
        atomicAdd(&ws[0], (double)s0);
        atomicAdd(&ws[1], (double)s1);
        atomicAdd(&ws[2], (double)s2);
        atomicAdd(&ws[3 + bimg],     (double)s3);
        atomicAdd(&ws[3 + B + bimg], (double)s4);
    }
}

__global__ void loss_final(const double* __restrict__ ws, float* __restrict__ out) {
    const int lane = threadIdx.x;
    double v = 0.0;
    if (lane < B) {
        double npos = ws[3 + lane];
        if (npos < 1.0) npos = 1.0;
        v = ws[3 + B + lane] / npos;
    }
    #pragma unroll
    for (int off = 32; off > 0; off >>= 1) v += __shfl_down(v, off);

    if (lane == 0) {
        const double inv = 1.0 / ((double)N * (double)B);
        double avg_ciou   = ws[0] * inv;
        double avg_cls    = ws[1] * inv;
        double avg_obj    = ws[2] * inv;
        double avg_posobj = v / (double)B;

        double t1 = 0.5 * avg_ciou;   // BOX_W
        double t2 = 1.5 * avg_obj;    // OBJ_W
        double t3 = 1.5 * avg_cls;    // CLS_W
        out[0] = (float)(t1 + t2 + t3);
        out[1] = (float)t1;
        out[2] = (float)t2;
        out[3] = (float)t3;
        out[4] = (float)avg_posobj;
    }
}

extern "C" void kernel_launch(void* const* d_in, const int* in_sizes, int n_in,
                              void* d_out, int out_size, void* d_ws, size_t ws_size,
                              hipStream_t stream) {
    const float* outputs = (const float*)d_in[0];
    const float* targets = (const float*)d_in[1];
    double* ws = (double*)d_ws;

    hipMemsetAsync(ws, 0, WS_DOUBLES * sizeof(double), stream);
    loss_main<<<BLOCKS, THREADS, 0, stream>>>(outputs, targets, ws);
    loss_final<<<1, 64, 0, stream>>>(ws, (float*)d_out);
}